// Round 6
// baseline (19758.351 us; speedup 1.0000x reference)
//
#include <hip/hip_runtime.h>
#include <hip/hip_cooperative_groups.h>

namespace cg = cooperative_groups;

// rnn_phy R6. R5 post-mortem: 1 wave/SIMD (Occupancy 12.4%) => pure latency starvation
// (VALUBusy 9.9%, HBM 1.5%). R6: 512 threads/block (2 waves/SIMD), K-split GEMVs,
// FF1 with 4 interleaved load streams, attention rebalanced to 160 1-item blocks.
// Same flush-free coherent design: Q/K/V/O via relaxed SYSTEM-scope atomics; monotonic
// counter barrier (186 total); one real grid.sync after weight packing.

#define Dd 130
#define DP 132
#define Hh 128
#define FFf 2048
#define NT 512

struct Args {
  const float *Tracks,*W_emb,*b_emb,*W_ih,*W_hh,*b_ih,*b_hh;
  const float *qkv_w,*qkv_b,*out_w,*out_b,*ff1_w,*ff1_b,*ff2_w,*ff2_b;
  const float *ln1_s,*ln1_b,*ln2_s,*ln2_b;
  const float *W_sp,*b_sp,*W_p1,*b_p1,*W_p2,*b_p2,*W_pl,*b_pl;
  float *X,*Q,*Kb,*V,*O,*Sh,*C,*X1,*X2;
  float *qkvP,*outP,*ff1P,*WspP;
  unsigned *flags;
  float *outp;
};

__device__ __forceinline__ float sigm(float x){ return 1.f/(1.f+__expf(-x)); }
__device__ __forceinline__ float dot4(float4 a, float4 b){ return a.x*b.x+a.y*b.y+a.z*b.z+a.w*b.w; }

__device__ __forceinline__ float cload(const float* p){
  return __hip_atomic_load(p, __ATOMIC_RELAXED, __HIP_MEMORY_SCOPE_SYSTEM);
}
__device__ __forceinline__ void cstore(float* p, float v){
  __hip_atomic_store(p, v, __ATOMIC_RELAXED, __HIP_MEMORY_SCOPE_SYSTEM);
}

// flush-free grid barrier: monotonic counter; __syncthreads drains each wave's vmcnt first.
__device__ void lbar(unsigned* cnt, unsigned target){
  __syncthreads();
  if (threadIdx.x==0){
    __hip_atomic_fetch_add(cnt, 1u, __ATOMIC_RELAXED, __HIP_MEMORY_SCOPE_SYSTEM);
    int guard=0;
    while (__hip_atomic_load(cnt, __ATOMIC_RELAXED, __HIP_MEMORY_SCOPE_SYSTEM) < target){
      __builtin_amdgcn_s_sleep(2);
      if (++guard > (1<<19)) break;
    }
  }
  __syncthreads();
}

// ---- weight packing ----
__device__ void ph_pack(const Args& a){
  int gid = blockIdx.x*NT + threadIdx.x, gsz = 256*NT;
  for (int idx=gid; idx<3*392*132; idx+=gsz){
    int j=idx%132, row=(idx/132)%392, l=idx/(132*392);
    a.qkvP[idx] = (row<390 && j<130)? a.qkv_w[(l*390+row)*130+j] : 0.f;
  }
  for (int idx=gid; idx<3*130*132; idx+=gsz){
    int j=idx%132, row=(idx/132)%130, l=idx/(132*130);
    a.outP[idx] = (j<130)? a.out_w[(l*130+row)*130+j] : 0.f;
  }
  for (int idx=gid; idx<3*2048*132; idx+=gsz){
    int j=idx%132, row=(idx/132)%2048, l=idx/(132*2048);
    a.ff1P[idx] = (j<130)? a.ff1_w[(l*2048+row)*130+j] : 0.f;
  }
  for (int idx=gid; idx<128*132; idx+=gsz){
    int j=idx%132, row=idx/132;
    a.WspP[idx] = (j<130)? a.W_sp[row*130+j] : 0.f;
  }
  if (gid==0) a.flags[0] = 0u;
}

// ---- LSTM + embedding, rows 2b,2b+1. 512 gate jobs, 1/thread ----
__device__ void ph_lstm(const Args& a, float* sm, int b, int xin_mode, int tstep, int p, int zero){
  int r0=2*b, tid=threadIdx.x;
  float* xe  = sm;        // [2][64]
  float* xh  = sm+128;    // [2][128]
  float* xin = sm+384;    // [2][4]
  float* graw= sm+392;    // [2][512]
  if (tid<8){ int r=tid>>2, j=tid&3;
    xin[tid] = (xin_mode==0)? a.Tracks[((r0+r)*20+tstep)*5+1+j] : a.outp[(r0+r)*40+p*4+j]; }
  if (tid<256){ int r=tid>>7, u=tid&127;
    xh[r*128+u] = zero? 0.f : a.Sh[(r0+r)*Hh+u]; }
  __syncthreads();
  if (tid<128){ int r=tid>>6, e=tid&63;
    float s=a.b_emb[e];
    #pragma unroll
    for(int j=0;j<4;j++) s+=xin[r*4+j]*a.W_emb[e*4+j];
    xe[r*64+e]=s; }
  __syncthreads();
  {
    const float4* xe0=(const float4*)xe;   const float4* xe1=(const float4*)(xe+64);
    const float4* xh0=(const float4*)xh;   const float4* xh1=(const float4*)(xh+128);
    int gr = tid;
    float acc0=0.f, acc1=0.f;
    const float4* wi=(const float4*)(a.W_ih + gr*64);
    const float4* wh=(const float4*)(a.W_hh + gr*128);
    #pragma unroll 4
    for(int j=0;j<16;j++){ float4 w=wi[j]; acc0+=dot4(w,xe0[j]); acc1+=dot4(w,xe1[j]); }
    #pragma unroll 4
    for(int j=0;j<32;j++){ float4 w=wh[j]; acc0+=dot4(w,xh0[j]); acc1+=dot4(w,xh1[j]); }
    float bb=a.b_ih[gr]+a.b_hh[gr];
    graw[gr]=acc0+bb; graw[512+gr]=acc1+bb;
  }
  __syncthreads();
  if (tid<256){ int r=tid>>7, u=tid&127, rr=r0+r;
    float* g_=graw+r*512;
    float gi=g_[u], gf=g_[128+u], gg=g_[256+u], go=g_[384+u];
    float cp = zero? 0.f : a.C[rr*Hh+u];
    float c2 = sigm(gf)*cp + sigm(gi)*tanhf(gg);
    a.C[rr*Hh+u]=c2;
    a.X[rr*DP+u]=sigm(go)*tanhf(c2);
    if (u<2){ a.X[rr*DP+128+u]=xin[r*4+u]; a.X[rr*DP+130+u]=0.f; }
  }
  __syncthreads();
}

// ---- Sh = X @ W_sp^T + b_sp. 512 jobs = (half,r,c), K split 17/16 f4 ----
__device__ void ph_proj(const Args& a, float* sm, int b){
  int r0=2*b, tid=threadIdx.x;
  float* xr=sm;          // [2][132]
  float* ps=sm+264;      // 512
  if (tid<66) ((float4*)xr)[tid] = ((const float4*)(a.X + r0*DP))[tid];
  __syncthreads();
  { int half=tid>>8, r=(tid>>7)&1, c=tid&127;
    const float4* w=(const float4*)(a.WspP + c*132);
    const float4* x4=(const float4*)(xr + r*132);
    int j0 = half? 17:0, j1 = half? 33:17;
    float acc=0.f;
    #pragma unroll 4
    for(int j=j0;j<j1;j++) acc+=dot4(w[j],x4[j]);
    ps[tid]=acc; }
  __syncthreads();
  if (tid<256){ int r=tid>>7, c=tid&127;
    a.Sh[(r0+r)*Hh+c] = ps[tid]+ps[tid+256] + a.b_sp[c]; }
  __syncthreads();
}

// ---- out = relu(in@W^T+b)+in, K=128, K-split 16/16 ----
__device__ void ph_mlp(const Args& a, float* sm, int b, const float* inp, const float* W, const float* bias, float* outp){
  int r0=2*b, tid=threadIdx.x;
  float* xr=sm;          // [2][128]
  float* ps=sm+256;      // 512
  if (tid<64) ((float4*)xr)[tid] = ((const float4*)(inp + r0*Hh))[tid];
  __syncthreads();
  { int half=tid>>8, r=(tid>>7)&1, c=tid&127;
    const float4* w=(const float4*)(W + c*128);
    const float4* x4=(const float4*)(xr + r*128);
    int j0 = half*16;
    float acc=0.f;
    #pragma unroll 4
    for(int j=j0;j<j0+16;j++) acc+=dot4(w[j],x4[j]);
    ps[tid]=acc; }
  __syncthreads();
  if (tid<256){ int r=tid>>7, c=tid&127;
    outp[(r0+r)*Hh+c] = fmaxf(ps[tid]+ps[tid+256]+bias[c],0.f) + xr[r*128+c]; }
  __syncthreads();
}

// ---- QKV: 780 outputs, coherent stores ----
__device__ void ph_qkv(const Args& a, float* sm, int b, int l){
  int r0=2*b, tid=threadIdx.x;
  float* xr=sm;
  if (tid<66) ((float4*)xr)[tid] = ((const float4*)(a.X + r0*DP))[tid];
  __syncthreads();
  const float* qb=a.qkv_b+l*390;
  for (int jj=tid; jj<780; jj+=NT){
    int c=jj>>1, r=jj&1, rr=r0+r;
    const float4* w=(const float4*)(a.qkvP + (l*392+c)*132);
    const float4* x4=(const float4*)(xr + r*132);
    float acc=0.f;
    #pragma unroll 4
    for(int j=0;j<33;j++) acc+=dot4(w[j],x4[j]);
    acc += qb[c];
    if (c<130)      cstore(a.Q +rr*DP+c,       acc);
    else if (c<260) cstore(a.Kb+rr*DP+(c-130), acc);
    else            cstore(a.V +rr*DP+(c-260), acc);
  }
  __syncthreads();
}

// ---- attention: 160 items = (32-row tile x head), exactly one per block (balanced) ----
__device__ void ph_attn(const Args& a, float* sm, int b){
  if (b>=160) return;
  float* kv=sm;          // 512 x 20
  float* qs=sm+10240;    // 32 x 13
  int tid=threadIdx.x, mg=tid&15, ii=tid>>4;   // ii: 0..31 rows
  const float scale=0.27735009811f;  // 1/sqrt(13)
  int tile=b&15, head=b>>4;
  int r0=tile*32, hc=head*13;
  for (int idx=tid; idx<512*13; idx+=NT){ int m=idx/13, d=idx-13*m; kv[m*20+d]=cload(a.Kb+m*DP+hc+d); }
  for (int idx=tid; idx<416; idx+=NT){ int r=idx/13, d=idx-13*r; qs[idx]=cload(a.Q+(r0+r)*DP+hc+d); }
  __syncthreads();
  float q[13];
  #pragma unroll
  for(int d=0;d<13;d++) q[d]=qs[ii*13+d]*scale;
  float4 q0={q[0],q[1],q[2],q[3]}, q1={q[4],q[5],q[6],q[7]}, q2={q[8],q[9],q[10],q[11]};
  float s[32], mx=-1e30f;
  #pragma unroll
  for(int k=0;k<32;k++){
    const float* kr=kv+(mg+16*k)*20;
    float v = dot4(q0,*(const float4*)kr) + dot4(q1,*(const float4*)(kr+4))
            + dot4(q2,*(const float4*)(kr+8)) + q[12]*kr[12];
    s[k]=v; mx=fmaxf(mx,v);
  }
  #pragma unroll
  for(int o=8;o>=1;o>>=1) mx=fmaxf(mx,__shfl_xor(mx,o,16));
  float sum=0.f;
  #pragma unroll
  for(int k=0;k<32;k++){ s[k]=__expf(s[k]-mx); sum+=s[k]; }
  #pragma unroll
  for(int o=8;o>=1;o>>=1) sum+=__shfl_xor(sum,o,16);
  float inv=1.f/sum;
  __syncthreads();
  for (int idx=tid; idx<512*13; idx+=NT){ int m=idx/13, d=idx-13*m; kv[m*20+d]=cload(a.V+m*DP+hc+d); }
  __syncthreads();
  float o_[13];
  #pragma unroll
  for(int d=0;d<13;d++) o_[d]=0.f;
  #pragma unroll
  for(int k=0;k<32;k++){
    const float* vr=kv+(mg+16*k)*20;
    float pw=s[k];
    float4 v0=*(const float4*)vr, v1=*(const float4*)(vr+4), v2=*(const float4*)(vr+8);
    o_[0]+=pw*v0.x; o_[1]+=pw*v0.y; o_[2] +=pw*v0.z; o_[3] +=pw*v0.w;
    o_[4]+=pw*v1.x; o_[5]+=pw*v1.y; o_[6] +=pw*v1.z; o_[7] +=pw*v1.w;
    o_[8]+=pw*v2.x; o_[9]+=pw*v2.y; o_[10]+=pw*v2.z; o_[11]+=pw*v2.w;
    o_[12]+=pw*vr[12];
  }
  #pragma unroll
  for(int d=0;d<13;d++){
    #pragma unroll
    for(int o=8;o>=1;o>>=1) o_[d]+=__shfl_xor(o_[d],o,16);
  }
  float outv=0.f;
  #pragma unroll
  for(int d=0;d<13;d++) if (mg==d) outv=o_[d];
  if (mg<13) cstore(a.O+(r0+ii)*DP+mg, outv*inv);
}

// ---- oproj + residual + LN1. 520 K-split jobs (17/16 f4) + LDS reduce ----
__device__ void ph_oln(const Args& a, float* sm, int b, int l){
  int r0=2*b, tid=threadIdx.x;
  float* orow=sm;        // [2][132]
  float* trow=sm+264;    // [2][132]
  float* ps  =sm+528;    // 520
  float* red1=sm+1048;   // 128
  float* red2=sm+1176;   // 128
  float* mi  =sm+1304;   // 4
  for (int idx=tid; idx<264; idx+=NT){ int r=idx/132, c=idx-132*r;
    orow[idx] = (c<130)? cload(a.O+(r0+r)*DP+c) : 0.f; }
  __syncthreads();
  for (int jj=tid; jj<520; jj+=NT){
    int half=jj/260, rem=jj-half*260, r=rem/130, c=rem-r*130;
    const float4* w=(const float4*)(a.outP+(l*130+c)*132);
    const float4* o4=(const float4*)(orow+r*132);
    int j0 = half? 17:0, j1 = half? 33:17;
    float acc=0.f;
    #pragma unroll 4
    for(int j=j0;j<j1;j++) acc+=dot4(w[j],o4[j]);
    ps[jj]=acc;
  }
  __syncthreads();
  const float* ob=a.out_b+l*Dd;
  if (tid<260){ int r=tid/130, c=tid-r*130;
    trow[r*132+c] = ps[tid]+ps[260+tid] + ob[c] + a.X[(r0+r)*DP+c]; }
  __syncthreads();
  if (tid<128){ int r=tid>>6, ln=tid&63;
    float s1=0.f,s2=0.f;
    for(int c=ln;c<130;c+=64){ float v=trow[r*132+c]; s1+=v; s2+=v*v; }
    red1[r*64+ln]=s1; red2[r*64+ln]=s2; }
  __syncthreads();
  if (tid<2){ float s1=0.f,s2=0.f;
    for(int k=0;k<64;k++){ s1+=red1[tid*64+k]; s2+=red2[tid*64+k]; }
    float m=s1/130.f; mi[tid]=m; mi[2+tid]=rsqrtf(s2/130.f-m*m+1e-5f); }
  __syncthreads();
  const float* ls=a.ln1_s+l*Dd; const float* lb=a.ln1_b+l*Dd;
  if (tid<260){ int r=tid/130, c=tid-r*130;
    a.X[(r0+r)*DP+c] = (trow[r*132+c]-mi[r])*mi[2+r]*ls[c] + lb[c]; }
  __syncthreads();
}

// ---- FF1 (4 interleaved h-streams) + FF2 (520 K-split jobs) + residual + LN2 ----
__device__ void ph_ff(const Args& a, float* sm, int b, int l){
  int r0=2*b, tid=threadIdx.x;
  float* xr  =sm;        // [2][132]
  float* ys  =sm+264;    // [2][2048]
  float* ps  =sm+4360;   // 520
  float* trow=sm+4880;   // [2][132]
  float* red1=sm+5144;   // 128
  float* red2=sm+5272;   // 128
  float* mi  =sm+5400;   // 4
  if (tid<66) ((float4*)xr)[tid]=((const float4*)(a.X+r0*DP))[tid];
  __syncthreads();
  // FF1: thread owns h = tid + 512k, k=0..3 -> 4 independent weight streams in one j-loop
  {
    const float* b1=a.ff1_b+l*FFf;
    const float4* x0=(const float4*)xr; const float4* x1=(const float4*)(xr+132);
    const float4* w0=(const float4*)(a.ff1P+(l*2048 + tid       )*132);
    const float4* w1=(const float4*)(a.ff1P+(l*2048 + tid + 512 )*132);
    const float4* w2=(const float4*)(a.ff1P+(l*2048 + tid + 1024)*132);
    const float4* w3=(const float4*)(a.ff1P+(l*2048 + tid + 1536)*132);
    float a00=0,a01=0,a10=0,a11=0,a20=0,a21=0,a30=0,a31=0;
    #pragma unroll 3
    for(int j=0;j<33;j++){
      float4 xa=x0[j], xb=x1[j];
      float4 wa=w0[j], wb=w1[j], wc=w2[j], wd=w3[j];
      a00+=dot4(wa,xa); a01+=dot4(wa,xb);
      a10+=dot4(wb,xa); a11+=dot4(wb,xb);
      a20+=dot4(wc,xa); a21+=dot4(wc,xb);
      a30+=dot4(wd,xa); a31+=dot4(wd,xb);
    }
    float b0=b1[tid], bb1=b1[tid+512], b2=b1[tid+1024], b3=b1[tid+1536];
    ys[tid]        =fmaxf(a00+b0,0.f);  ys[2048+tid]      =fmaxf(a01+b0,0.f);
    ys[tid+512]    =fmaxf(a10+bb1,0.f); ys[2048+tid+512]  =fmaxf(a11+bb1,0.f);
    ys[tid+1024]   =fmaxf(a20+b2,0.f);  ys[2048+tid+1024] =fmaxf(a21+b2,0.f);
    ys[tid+1536]   =fmaxf(a30+b3,0.f);  ys[2048+tid+1536] =fmaxf(a31+b3,0.f);
  }
  __syncthreads();
  // FF2: jobs (half,r,c) over K halves of 1024
  for (int jj=tid; jj<520; jj+=NT){
    int half=jj/260, rem=jj-half*260, r=rem/130, c=rem-r*130;
    const float4* w =(const float4*)(a.ff2_w+(l*130+c)*2048 + half*1024);
    const float4* y4=(const float4*)(ys + r*2048 + half*1024);
    float acc=0.f;
    #pragma unroll 8
    for(int k=0;k<256;k++) acc+=dot4(w[k],y4[k]);
    ps[jj]=acc;
  }
  __syncthreads();
  const float* f2b=a.ff2_b+l*Dd;
  if (tid<260){ int r=tid/130, c=tid-r*130;
    trow[r*132+c]=ps[tid]+ps[260+tid]+f2b[c]+xr[r*132+c]; }
  __syncthreads();
  if (tid<128){ int r=tid>>6, ln=tid&63;
    float s1=0.f,s2=0.f;
    for(int c=ln;c<130;c+=64){ float v=trow[r*132+c]; s1+=v; s2+=v*v; }
    red1[r*64+ln]=s1; red2[r*64+ln]=s2; }
  __syncthreads();
  if (tid<2){ float s1=0.f,s2=0.f;
    for(int k=0;k<64;k++){ s1+=red1[tid*64+k]; s2+=red2[tid*64+k]; }
    float m=s1/130.f; mi[tid]=m; mi[2+tid]=rsqrtf(s2/130.f-m*m+1e-5f); }
  __syncthreads();
  const float* ls=a.ln2_s+l*Dd; const float* lb=a.ln2_b+l*Dd;
  if (tid<260){ int r=tid/130, c=tid-r*130;
    a.X[(r0+r)*DP+c]=(trow[r*132+c]-mi[r])*mi[2+r]*ls[c]+lb[c]; }
  __syncthreads();
}

// ---- pred head ----
__device__ void ph_pout(const Args& a, float* sm, int b, int p){
  int r0=2*b, tid=threadIdx.x;
  float* x2=sm;        // [2][128]
  float* red=sm+256;   // [4][16]
  if (tid<64) ((float4*)x2)[tid]=((const float4*)(a.X2+r0*Hh))[tid];
  __syncthreads();
  if (tid<64){ int jr=tid&3, kc=tid>>2;
    int r=jr>>1, j=jr&1;
    float s=0.f;
    for (int v=kc*8; v<kc*8+8; v++) s += x2[r*128+v]*a.W_pl[j*Hh+v];
    red[jr*16+kc]=s; }
  __syncthreads();
  if (tid<4){ int r=tid>>1, j=tid&1, rr=r0+r;
    float av=a.b_pl[j];
    for(int k=0;k<16;k++) av+=red[tid*16+k];
    float cf0, cf2;
    if (p==0){ cf0=a.Tracks[(rr*20+19)*5+1+j]; cf2=a.Tracks[(rr*20+19)*5+3+j]; }
    else     { cf0=a.outp[rr*40+(p-1)*4+j];    cf2=a.outp[rr*40+(p-1)*4+2+j]; }
    float vv=av*0.1f+cf2;
    float pn=av*0.005f+vv*0.1f+cf0;
    a.outp[rr*40+p*4+j]  =pn;
    a.outp[rr*40+p*4+2+j]=vv;
  }
  __syncthreads();
}

// ================= persistent cooperative kernel =================
__global__ void __launch_bounds__(NT,2) persist(Args a){
  cg::grid_group grid = cg::this_grid();
  __shared__ float sm[10688];   // 42,752 B
  int b = blockIdx.x;
  unsigned rnd = 0;

  ph_pack(a);
  grid.sync();   // the ONLY heavy sync: publishes packed weights + zeroed barrier counter

  auto layers = [&](){
    for (int l=0;l<3;l++){
      lbar(a.flags, (++rnd)*256u);
      ph_attn(a, sm, b);
      lbar(a.flags, (++rnd)*256u);
      ph_oln(a, sm, b, l);
      ph_ff (a, sm, b, l);
      if (l<2) ph_qkv(a, sm, b, l+1);
    }
  };

  ph_lstm(a, sm, b, 0, 0, 0, 1);
  ph_qkv (a, sm, b, 0);
  layers();
  for (int t=0;t<20;t++){
    ph_proj(a, sm, b);
    ph_lstm(a, sm, b, 0, t, 0, 0);
    ph_qkv (a, sm, b, 0);
    layers();
  }
  for (int p=0;p<10;p++){
    ph_proj(a, sm, b);
    ph_mlp (a, sm, b, a.Sh, a.W_p1, a.b_p1, a.X1);
    ph_mlp (a, sm, b, a.X1, a.W_p2, a.b_p2, a.X2);
    ph_pout(a, sm, b, p);
    if (p<9){
      ph_lstm(a, sm, b, 1, 0, p, 0);
      ph_qkv (a, sm, b, 0);
      layers();
    }
  }
}

// ================= fallback per-phase kernels (same phase functions) =================
#define OPF_OLNFF 1
#define OPF_PROJ  2
#define OPF_PRED  4
#define OPF_LSTM  8
#define OPF_QKV  16

__global__ __launch_bounds__(NT) void g_pack(Args a){ ph_pack(a); }
__global__ __launch_bounds__(NT) void g_attn(Args a){ __shared__ float sm[10688]; ph_attn(a, sm, blockIdx.x); }
__global__ __launch_bounds__(NT) void g_macro(Args a, int ops, int l, int p, int t, int mode, int zero, int lq){
  __shared__ float sm[5408];
  int b = blockIdx.x;
  if (ops & OPF_OLNFF){ ph_oln(a, sm, b, l); ph_ff(a, sm, b, l); }
  if (ops & OPF_PROJ )  ph_proj(a, sm, b);
  if (ops & OPF_PRED ){ ph_mlp(a, sm, b, a.Sh, a.W_p1, a.b_p1, a.X1);
                        ph_mlp(a, sm, b, a.X1, a.W_p2, a.b_p2, a.X2);
                        ph_pout(a, sm, b, p); }
  if (ops & OPF_LSTM )  ph_lstm(a, sm, b, mode, t, p, zero);
  if (ops & OPF_QKV  )  ph_qkv(a, sm, b, lq);
}

extern "C" void kernel_launch(void* const* d_in, const int* in_sizes, int n_in,
                              void* d_out, int out_size, void* d_ws, size_t ws_size,
                              hipStream_t stream) {
  (void)in_sizes; (void)n_in; (void)out_size; (void)ws_size;
  Args A;
  const float* const* in = (const float* const*)d_in;
  A.Tracks=in[0]; A.W_emb=in[1]; A.b_emb=in[2]; A.W_ih=in[3]; A.W_hh=in[4]; A.b_ih=in[5]; A.b_hh=in[6];
  A.qkv_w=in[7]; A.qkv_b=in[8]; A.out_w=in[9]; A.out_b=in[10];
  A.ff1_w=in[11]; A.ff1_b=in[12]; A.ff2_w=in[13]; A.ff2_b=in[14];
  A.ln1_s=in[15]; A.ln1_b=in[16]; A.ln2_s=in[17]; A.ln2_b=in[18];
  A.W_sp=in[19]; A.b_sp=in[20]; A.W_p1=in[21]; A.b_p1=in[22]; A.W_p2=in[23]; A.b_p2=in[24];
  A.W_pl=in[25]; A.b_pl=in[26];
  float* ws = (float*)d_ws;
  A.X    = ws;                 // 512*132 = 67584
  A.Q    = ws + 67584;
  A.Kb   = ws + 135168;
  A.V    = ws + 202752;
  A.O    = ws + 270336;
  A.Sh   = ws + 337920;        // 512*128
  A.C    = ws + 403456;
  A.X1   = ws + 468992;
  A.X2   = ws + 534528;
  A.qkvP = ws + 600064;        // 3*392*132 = 155232
  A.outP = ws + 755296;        // 3*130*132 = 51480
  A.ff1P = ws + 806776;        // 3*2048*132 = 811008
  A.WspP = ws + 1617784;       // 128*132 = 16896
  A.flags= (unsigned*)(ws + 1634680);
  A.outp = (float*)d_out;

  void* kargs[] = { (void*)&A };
  hipError_t err = hipLaunchCooperativeKernel((const void*)persist, dim3(256), dim3(NT), kargs, 0, stream);
  if (err == hipSuccess) return;

  // ---------- fallback: same phases as individual kernels ----------
  dim3 B(NT);
  g_pack<<<dim3(256), B, 0, stream>>>(A);
  auto layers = [&](){
    for (int l=0;l<3;l++){
      g_attn<<<dim3(256), B, 0, stream>>>(A);
      int ops = OPF_OLNFF | ((l<2) ? OPF_QKV : 0);
      g_macro<<<dim3(256), B, 0, stream>>>(A, ops, l, 0, 0, 0, 0, l+1);
    }
  };
  g_macro<<<dim3(256), B, 0, stream>>>(A, OPF_LSTM|OPF_QKV, 0, 0, 0, 0, 1, 0);
  layers();
  for (int t=0;t<20;t++){
    g_macro<<<dim3(256), B, 0, stream>>>(A, OPF_PROJ|OPF_LSTM|OPF_QKV, 0, 0, t, 0, 0, 0);
    layers();
  }
  for (int p=0;p<10;p++){
    int ops = OPF_PROJ|OPF_PRED | ((p<9) ? (OPF_LSTM|OPF_QKV) : 0);
    g_macro<<<dim3(256), B, 0, stream>>>(A, ops, 0, p, 0, 1, 0, 0);
    if (p<9) layers();
  }
}